// Round 9
// baseline (303.616 us; speedup 1.0000x reference)
//
#include <hip/hip_runtime.h>

// Neural CDE forward, fused persistent kernel, split-f16 MFMA, transposed
// GEMMs. Round-9 = round-8 (16 waves, 4/SIMD occupancy) + arch-VGPR squeeze
// to kill the in-loop scratch spill (r8: WRITE_SIZE 9 MB, arch budget 64):
//  - cnext coeff load moved AFTER barrier 1 (pinned by sched_barrier(0));
//    live range = GEMM2 phase only, latency hidden under 24 MFMAs (L2-hot).
//  - GEMM1 as two sequential kt half-blocks: peak operand liveness 16 -> 8.
//  - b1 bias lives in the spare 16B of each w1f LDS slot (read per step).
//  - z writeback + readout partial computed on owner lanes only.
// Numerics unchanged: split-f16 (hi+lo), 3 MFMA terms per tile, f32 state.

#define NBLK 256
#define NT   1024
#define RB   16
#define T_LEN 166
#define NSTEP 165
#define IC   8
#define HID  64
#define MW   128
#define NF   512

typedef _Float16 half8 __attribute__((ext_vector_type(8)));
typedef _Float16 half4 __attribute__((ext_vector_type(4)));
typedef float    f32x4 __attribute__((ext_vector_type(4)));

__device__ __forceinline__ float fast_tanh(float x) {
    float e = __expf(2.0f * x);
    return 1.0f - 2.0f * __builtin_amdgcn_rcpf(e + 1.0f);
}

__device__ __forceinline__ void bar_lgkm() {
    asm volatile("s_waitcnt lgkmcnt(0)" ::: "memory");
    __builtin_amdgcn_s_barrier();
    __builtin_amdgcn_sched_barrier(0);
}

// x + x[lane^16] on all lanes (swap-direction independent).
__device__ __forceinline__ float sum_xor16(float x) {
#if __has_builtin(__builtin_amdgcn_permlane16_swap)
    auto r = __builtin_amdgcn_permlane16_swap(__float_as_uint(x), __float_as_uint(x), false, false);
    return __uint_as_float(r[0]) + __uint_as_float(r[1]);
#else
    return x + __shfl_xor(x, 16, 64);
#endif
}
// x + x[lane^32] on all lanes.
__device__ __forceinline__ float sum_xor32(float x) {
#if __has_builtin(__builtin_amdgcn_permlane32_swap)
    auto r = __builtin_amdgcn_permlane32_swap(__float_as_uint(x), __float_as_uint(x), false, false);
    return __uint_as_float(r[0]) + __uint_as_float(r[1]);
#else
    return x + __shfl_xor(x, 32, 64);
#endif
}

__global__ __launch_bounds__(NT, 4)
void cde_fused(const float* __restrict__ u0, const float* __restrict__ coeffs,
               const float* __restrict__ W1, const float* __restrict__ b1,
               const float* __restrict__ W2, const float* __restrict__ b2,
               const float* __restrict__ Wi, const float* __restrict__ bi,
               const float* __restrict__ Wr, const float* __restrict__ br,
               float* __restrict__ out)
{
    __shared__ __align__(16) unsigned char hh[RB * 256];    // h hi: 16 x 128 f16 (swizzled)
    __shared__ __align__(16) unsigned char hl[RB * 256];    // h lo
    __shared__ __align__(16) unsigned char zh[RB * 128];    // z hi: 16 x 64 f16 (swizzled)
    __shared__ __align__(16) unsigned char zl[RB * 128];    // z lo
    __shared__ __align__(16) unsigned char w1f[8 * 64 * 80];// W1 frags + b1 per (wave,lane)
    __shared__ float part[16][17];                          // readout partials [wave][batch]

    const int tid  = threadIdx.x;
    const int lane = tid & 63;
    const int w    = tid >> 6;      // wave 0..15
    const int l15  = lane & 15;     // batch row in MFMA D
    const int lq   = lane >> 4;     // 0..3
    const bool hi32 = (lane & 32) != 0;
    const int swzr = (l15 & 7) << 4;
    const int b0   = blockIdx.x * RB;

    // ---- stage split W2 (2 ntiles per wave) into registers/AGPRs ----
    half8 w2h[8], w2l[8];
    #pragma unroll
    for (int q = 0; q < 2; ++q) {
        #pragma unroll
        for (int kt = 0; kt < 4; ++kt) {
            const int krow = kt * 32 + lq * 8;
            const int ncol = (w * 2 + q) * 16 + l15;
            half8 vh, vl;
            #pragma unroll
            for (int j = 0; j < 8; ++j) {
                const float x = W2[(krow + j) * NF + ncol];
                const _Float16 hi = (_Float16)x;
                vh[j] = hi; vl[j] = (_Float16)(x - (float)hi);
            }
            w2h[q * 4 + kt] = vh; w2l[q * 4 + kt] = vl;
        }
    }
    f32x4 b2v[2];
    #pragma unroll
    for (int q = 0; q < 2; ++q)
        b2v[q] = *(const f32x4*)(b2 + (w * 2 + q) * 16 + lq * 4);

    // ---- stage split W1 fragments + b1 into LDS (waves 0-7) ----
    const int fbase = (w * 64 + lane) * 80;   // 80B slot: 4x16B frags + 16B b1
    if (w < 8) {
        #pragma unroll
        for (int kt = 0; kt < 2; ++kt) {
            const int krow = kt * 32 + lq * 8;
            const int ncol = w * 16 + l15;
            half8 vh, vl;
            #pragma unroll
            for (int j = 0; j < 8; ++j) {
                const float x = W1[(krow + j) * MW + ncol];
                const _Float16 hi = (_Float16)x;
                vh[j] = hi; vl[j] = (_Float16)(x - (float)hi);
            }
            *(half8*)(w1f + fbase + kt * 16)      = vh;   // h0 @0, h1 @16
            *(half8*)(w1f + fbase + 32 + kt * 16) = vl;   // l0 @32, l1 @48
        }
        *(f32x4*)(w1f + fbase + 64) = *(const f32x4*)(b1 + w * 16 + lq * 4);
    }

    // readout weights for this wave's 4 channels (wave-uniform -> scalar)
    const int w_u = __builtin_amdgcn_readfirstlane(w);
    float wrs[4];
    #pragma unroll
    for (int j = 0; j < 4; ++j) wrs[j] = Wr[w_u * 4 + j];
    const float brv = br[0];

    // ---- z0: owner lane (lq==0) holds channels [4w, 4w+4) of batch l15 ----
    float z4[4];
    {
        float uu7[7];
        const float* ur = u0 + (size_t)(b0 + l15) * 7;
        #pragma unroll
        for (int c = 0; c < 7; ++c) uu7[c] = ur[c];
        #pragma unroll
        for (int j = 0; j < 4; ++j) {
            float a = bi[w * 4 + j];
            #pragma unroll
            for (int c = 0; c < 7; ++c) a = fmaf(uu7[c], Wi[c * HID + w * 4 + j], a);
            z4[j] = a;
        }
    }
    if (lq == 0) {
        half4 h4, l4;
        float rp = 0.f;
        #pragma unroll
        for (int j = 0; j < 4; ++j) {
            const _Float16 hi = (_Float16)z4[j];
            h4[j] = hi; l4[j] = (_Float16)(z4[j] - (float)hi);
            rp = fmaf(z4[j], wrs[j], rp);
        }
        const int zoff = l15 * 128 + ((w * 8) ^ swzr);
        *(half4*)(zh + zoff) = h4;
        *(half4*)(zl + zoff) = l4;
        part[w][l15] = rp;
    }
    // per-lane coeff stream: 16B chunk (i = (lq&1)*4 .. +3) of row l15
    const float* cbase = coeffs + (size_t)(b0 + l15) * T_LEN * IC + (lq & 1) * 4;
    f32x4 ccur = *(const f32x4*)(cbase);
    __syncthreads();

    for (int t = 0; t < NSTEP; ++t) {
        // ---- readout finalize for state t (wave 15, idle in GEMM1 phase) ----
        if (w == 15) {
            float v = part[lq * 4 + 0][l15] + part[lq * 4 + 1][l15]
                    + part[lq * 4 + 2][l15] + part[lq * 4 + 3][l15];
            v = sum_xor32(sum_xor16(v));
            if (lq == 0) out[(size_t)(b0 + l15) * T_LEN + t] = v + brv;
        }

        // ---- GEMM1 (waves 0-7): two sequential kt half-blocks ----
        if (w < 8) {
            f32x4 a1A = *(const f32x4*)(w1f + fbase + 64);     // b1 from LDS slot
            {
                const int zo0 = l15 * 128 + ((lq * 16) ^ swzr);
                const half8 fh   = *(const half8*)(w1f + fbase);
                const half8 fl   = *(const half8*)(w1f + fbase + 32);
                const half8 zfh0 = *(const half8*)(zh + zo0);
                const half8 zfl0 = *(const half8*)(zl + zo0);
                a1A = __builtin_amdgcn_mfma_f32_16x16x32_f16(fh, zfh0, a1A, 0, 0, 0);
                a1A = __builtin_amdgcn_mfma_f32_16x16x32_f16(fl, zfh0, a1A, 0, 0, 0);
                a1A = __builtin_amdgcn_mfma_f32_16x16x32_f16(fh, zfl0, a1A, 0, 0, 0);
            }
            {
                const int zo1 = l15 * 128 + ((64 + lq * 16) ^ swzr);
                const half8 fh   = *(const half8*)(w1f + fbase + 16);
                const half8 fl   = *(const half8*)(w1f + fbase + 48);
                const half8 zfh1 = *(const half8*)(zh + zo1);
                const half8 zfl1 = *(const half8*)(zl + zo1);
                a1A = __builtin_amdgcn_mfma_f32_16x16x32_f16(fh, zfh1, a1A, 0, 0, 0);
                a1A = __builtin_amdgcn_mfma_f32_16x16x32_f16(fl, zfh1, a1A, 0, 0, 0);
                a1A = __builtin_amdgcn_mfma_f32_16x16x32_f16(fh, zfl1, a1A, 0, 0, 0);
            }
            half4 ph, pl;
            #pragma unroll
            for (int r = 0; r < 4; ++r) {
                const float hv = fmaxf(a1A[r], 0.0f);
                const _Float16 hi = (_Float16)hv;
                ph[r] = hi; pl[r] = (_Float16)(hv - (float)hi);
            }
            const int hoff = l15 * 256 + ((w * 32 + lq * 8) ^ swzr);
            *(half4*)(hh + hoff) = ph;
            *(half4*)(hl + hoff) = pl;
        }
        bar_lgkm();

        // ---- coeff load for this step (pinned below barrier 1; hides
        //      under the 24 MFMAs; live range = GEMM2 phase only) ----
        const f32x4 cnext = *(const f32x4*)(cbase + (size_t)(t + 1) * IC);

        // ---- GEMM2 (all 16 waves, 2 ntiles each) ----
        f32x4 acc0 = b2v[0];
        f32x4 acc1 = b2v[1];
        #pragma unroll
        for (int kt = 0; kt < 4; ++kt) {
            const int off = l15 * 256 + ((kt * 64 + lq * 16) ^ swzr);
            const half8 bh = *(const half8*)(hh + off);
            const half8 bl = *(const half8*)(hl + off);
            acc0 = __builtin_amdgcn_mfma_f32_16x16x32_f16(w2h[kt],     bh, acc0, 0, 0, 0);
            acc1 = __builtin_amdgcn_mfma_f32_16x16x32_f16(w2h[4 + kt], bh, acc1, 0, 0, 0);
            acc0 = __builtin_amdgcn_mfma_f32_16x16x32_f16(w2l[kt],     bh, acc0, 0, 0, 0);
            acc1 = __builtin_amdgcn_mfma_f32_16x16x32_f16(w2l[4 + kt], bh, acc1, 0, 0, 0);
            acc0 = __builtin_amdgcn_mfma_f32_16x16x32_f16(w2h[kt],     bl, acc0, 0, 0, 0);
            acc1 = __builtin_amdgcn_mfma_f32_16x16x32_f16(w2h[4 + kt], bl, acc1, 0, 0, 0);
        }

        // ---- tanh + i-contraction + register z update ----
        // lane (l15,lq), q: f-cols n=(2w+q)*16+lq*4+r; i=(lq&1)*4+r; kh=4w+2q+(lq>>1)
        const f32x4 dxv = cnext - ccur;
        float s0 = 0.f, s1 = 0.f;
        #pragma unroll
        for (int r = 0; r < 4; ++r) {
            s0 = fmaf(fast_tanh(acc0[r]), dxv[r], s0);
            s1 = fmaf(fast_tanh(acc1[r]), dxv[r], s1);
        }
        {
            const float tt0 = sum_xor16(s0);
            const float uu0 = sum_xor32(hi32 ? tt0 : 0.f);
            z4[0] += tt0; z4[1] += uu0;
            const float tt1 = sum_xor16(s1);
            const float uu1 = sum_xor32(hi32 ? tt1 : 0.f);
            z4[2] += tt1; z4[3] += uu1;
        }
        ccur = cnext;
        // ---- writeback + readout partial (owner lanes only) ----
        if (lq == 0) {
            half4 h4, l4;
            float rp = 0.f;
            #pragma unroll
            for (int j = 0; j < 4; ++j) {
                const _Float16 hi = (_Float16)z4[j];
                h4[j] = hi; l4[j] = (_Float16)(z4[j] - (float)hi);
                rp = fmaf(z4[j], wrs[j], rp);
            }
            const int zoff = l15 * 128 + ((w * 8) ^ swzr);
            *(half4*)(zh + zoff) = h4;
            *(half4*)(zl + zoff) = l4;
            part[w][l15] = rp;
        }
        bar_lgkm();
    }

    // ---- final readout: state 165 ----
    if (w == 15) {
        float v = part[lq * 4 + 0][l15] + part[lq * 4 + 1][l15]
                + part[lq * 4 + 2][l15] + part[lq * 4 + 3][l15];
        v = sum_xor32(sum_xor16(v));
        if (lq == 0) out[(size_t)(b0 + l15) * T_LEN + NSTEP] = v + brv;
    }
}

extern "C" void kernel_launch(void* const* d_in, const int* in_sizes, int n_in,
                              void* d_out, int out_size, void* d_ws, size_t ws_size,
                              hipStream_t stream) {
    const float* u0     = (const float*)d_in[0];
    const float* coeffs = (const float*)d_in[1];
    const float* W1     = (const float*)d_in[2];
    const float* b1     = (const float*)d_in[3];
    const float* W2     = (const float*)d_in[4];
    const float* b2     = (const float*)d_in[5];
    const float* Wi     = (const float*)d_in[6];
    const float* bi     = (const float*)d_in[7];
    const float* Wr     = (const float*)d_in[8];
    const float* br     = (const float*)d_in[9];
    cde_fused<<<NBLK, NT, 0, stream>>>(u0, coeffs, W1, b1, W2, b2, Wi, bi, Wr, br,
                                       (float*)d_out);
}

// Round 10
// 299.442 us; speedup vs baseline: 1.0139x; 1.0139x over previous
//
#include <hip/hip_runtime.h>

// Neural CDE forward, fused persistent kernel, split-f16 MFMA, transposed
// GEMMs. Round-10 = round-8 schedule (cnext load at loop TOP: latency hides
// under all of GEMM1+barrier; r9's post-barrier load was the regression)
// + arch-VGPR squeeze to kill the in-loop scratch spill for real:
//  - b2 acc-init biases live in LDS planes b2s[2][16][64] (16B/lane,
//    conflict-free b128), read at GEMM2 start overlapping h-fragment reads.
//    Frees 8 persistent arch VGPRs.
//  - b1 bias lives in the spare 16B of each w1f slot (read at GEMM1 start,
//    hidden under the 8 other LDS fragment reads). Frees 4 more.
//  With launch_bounds(1024,4): total 128 regs = 64 AGPR (w2) + arch <= 64.
// Numerics unchanged: split-f16 (hi+lo), 3 MFMA terms per tile, f32 state.

#define NBLK 256
#define NT   1024
#define RB   16
#define T_LEN 166
#define NSTEP 165
#define IC   8
#define HID  64
#define MW   128
#define NF   512

typedef _Float16 half8 __attribute__((ext_vector_type(8)));
typedef _Float16 half4 __attribute__((ext_vector_type(4)));
typedef float    f32x4 __attribute__((ext_vector_type(4)));

__device__ __forceinline__ float fast_tanh(float x) {
    float e = __expf(2.0f * x);
    return 1.0f - 2.0f * __builtin_amdgcn_rcpf(e + 1.0f);
}

__device__ __forceinline__ void bar_lgkm() {
    asm volatile("s_waitcnt lgkmcnt(0)" ::: "memory");
    __builtin_amdgcn_s_barrier();
    __builtin_amdgcn_sched_barrier(0);
}

// x + x[lane^16] on all lanes (swap-direction independent).
__device__ __forceinline__ float sum_xor16(float x) {
#if __has_builtin(__builtin_amdgcn_permlane16_swap)
    auto r = __builtin_amdgcn_permlane16_swap(__float_as_uint(x), __float_as_uint(x), false, false);
    return __uint_as_float(r[0]) + __uint_as_float(r[1]);
#else
    return x + __shfl_xor(x, 16, 64);
#endif
}
// x + x[lane^32] on all lanes.
__device__ __forceinline__ float sum_xor32(float x) {
#if __has_builtin(__builtin_amdgcn_permlane32_swap)
    auto r = __builtin_amdgcn_permlane32_swap(__float_as_uint(x), __float_as_uint(x), false, false);
    return __uint_as_float(r[0]) + __uint_as_float(r[1]);
#else
    return x + __shfl_xor(x, 32, 64);
#endif
}

__global__ __launch_bounds__(NT, 4)
void cde_fused(const float* __restrict__ u0, const float* __restrict__ coeffs,
               const float* __restrict__ W1, const float* __restrict__ b1,
               const float* __restrict__ W2, const float* __restrict__ b2,
               const float* __restrict__ Wi, const float* __restrict__ bi,
               const float* __restrict__ Wr, const float* __restrict__ br,
               float* __restrict__ out)
{
    __shared__ __align__(16) unsigned char hh[RB * 256];    // h hi: 16 x 128 f16 (swizzled)
    __shared__ __align__(16) unsigned char hl[RB * 256];    // h lo
    __shared__ __align__(16) unsigned char zh[RB * 128];    // z hi: 16 x 64 f16 (swizzled)
    __shared__ __align__(16) unsigned char zl[RB * 128];    // z lo
    __shared__ __align__(16) unsigned char w1f[8 * 64 * 80];// W1 frags + b1 per (wave,lane)
    __shared__ __align__(16) unsigned char b2s[2 * 16 * 64 * 16]; // b2 acc-init planes
    __shared__ float part[16][17];                          // readout partials [wave][batch]

    const int tid  = threadIdx.x;
    const int lane = tid & 63;
    const int w    = tid >> 6;      // wave 0..15
    const int l15  = lane & 15;     // batch row in MFMA D
    const int lq   = lane >> 4;     // 0..3
    const bool hi32 = (lane & 32) != 0;
    const int swzr = (l15 & 7) << 4;
    const int b0   = blockIdx.x * RB;

    // ---- stage split W2 (2 ntiles per wave) into registers/AGPRs ----
    half8 w2h[8], w2l[8];
    #pragma unroll
    for (int q = 0; q < 2; ++q) {
        #pragma unroll
        for (int kt = 0; kt < 4; ++kt) {
            const int krow = kt * 32 + lq * 8;
            const int ncol = (w * 2 + q) * 16 + l15;
            half8 vh, vl;
            #pragma unroll
            for (int j = 0; j < 8; ++j) {
                const float x = W2[(krow + j) * NF + ncol];
                const _Float16 hi = (_Float16)x;
                vh[j] = hi; vl[j] = (_Float16)(x - (float)hi);
            }
            w2h[q * 4 + kt] = vh; w2l[q * 4 + kt] = vl;
        }
    }
    // ---- stage b2 acc-init into LDS planes (16B per lane, conflict-free) ----
    const int b2slot = (w * 64 + lane) * 16;
    *(f32x4*)(b2s + b2slot)         = *(const f32x4*)(b2 + (w * 2 + 0) * 16 + lq * 4);
    *(f32x4*)(b2s + 16384 + b2slot) = *(const f32x4*)(b2 + (w * 2 + 1) * 16 + lq * 4);

    // ---- stage split W1 fragments + b1 into LDS (waves 0-7) ----
    const int fbase = (w * 64 + lane) * 80;   // 80B slot: 4x16B frags + 16B b1
    if (w < 8) {
        #pragma unroll
        for (int kt = 0; kt < 2; ++kt) {
            const int krow = kt * 32 + lq * 8;
            const int ncol = w * 16 + l15;
            half8 vh, vl;
            #pragma unroll
            for (int j = 0; j < 8; ++j) {
                const float x = W1[(krow + j) * MW + ncol];
                const _Float16 hi = (_Float16)x;
                vh[j] = hi; vl[j] = (_Float16)(x - (float)hi);
            }
            *(half8*)(w1f + fbase + kt * 16)      = vh;   // h0 @0, h1 @16
            *(half8*)(w1f + fbase + 32 + kt * 16) = vl;   // l0 @32, l1 @48
        }
        *(f32x4*)(w1f + fbase + 64) = *(const f32x4*)(b1 + w * 16 + lq * 4);
    }

    // readout weights for this wave's 4 channels (wave-uniform -> scalar)
    const int w_u = __builtin_amdgcn_readfirstlane(w);
    float wrs[4];
    #pragma unroll
    for (int j = 0; j < 4; ++j) wrs[j] = Wr[w_u * 4 + j];
    const float brv = br[0];

    // ---- z0: owner lane (lq==0) holds channels [4w, 4w+4) of batch l15 ----
    float z4[4];
    {
        float uu7[7];
        const float* ur = u0 + (size_t)(b0 + l15) * 7;
        #pragma unroll
        for (int c = 0; c < 7; ++c) uu7[c] = ur[c];
        #pragma unroll
        for (int j = 0; j < 4; ++j) {
            float a = bi[w * 4 + j];
            #pragma unroll
            for (int c = 0; c < 7; ++c) a = fmaf(uu7[c], Wi[c * HID + w * 4 + j], a);
            z4[j] = a;
        }
    }
    if (lq == 0) {
        half4 h4, l4;
        float rp = 0.f;
        #pragma unroll
        for (int j = 0; j < 4; ++j) {
            const _Float16 hi = (_Float16)z4[j];
            h4[j] = hi; l4[j] = (_Float16)(z4[j] - (float)hi);
            rp = fmaf(z4[j], wrs[j], rp);
        }
        const int zoff = l15 * 128 + ((w * 8) ^ swzr);
        *(half4*)(zh + zoff) = h4;
        *(half4*)(zl + zoff) = l4;
        part[w][l15] = rp;
    }
    // per-lane coeff stream: 16B chunk (i = (lq&1)*4 .. +3) of row l15
    const float* cbase = coeffs + (size_t)(b0 + l15) * T_LEN * IC + (lq & 1) * 4;
    f32x4 ccur = *(const f32x4*)(cbase);
    __syncthreads();

    for (int t = 0; t < NSTEP; ++t) {
        // prefetch next coeff chunk at loop TOP (hides under GEMM1+barrier)
        const f32x4 cnext = *(const f32x4*)(cbase + (size_t)(t + 1) * IC);

        // ---- readout finalize for state t (wave 15, idle in GEMM1 phase) ----
        if (w == 15) {
            float v = part[lq * 4 + 0][l15] + part[lq * 4 + 1][l15]
                    + part[lq * 4 + 2][l15] + part[lq * 4 + 3][l15];
            v = sum_xor32(sum_xor16(v));
            if (lq == 0) out[(size_t)(b0 + l15) * T_LEN + t] = v + brv;
        }

        // ---- GEMM1 (waves 0-7): h^T = W1^T @ z^T, relu, split store ----
        if (w < 8) {
            f32x4 a1A = *(const f32x4*)(w1f + fbase + 64);     // b1 from LDS slot
            {
                const int zo0 = l15 * 128 + ((lq * 16) ^ swzr);
                const half8 fh   = *(const half8*)(w1f + fbase);
                const half8 fl   = *(const half8*)(w1f + fbase + 32);
                const half8 zfh0 = *(const half8*)(zh + zo0);
                const half8 zfl0 = *(const half8*)(zl + zo0);
                a1A = __builtin_amdgcn_mfma_f32_16x16x32_f16(fh, zfh0, a1A, 0, 0, 0);
                a1A = __builtin_amdgcn_mfma_f32_16x16x32_f16(fl, zfh0, a1A, 0, 0, 0);
                a1A = __builtin_amdgcn_mfma_f32_16x16x32_f16(fh, zfl0, a1A, 0, 0, 0);
            }
            {
                const int zo1 = l15 * 128 + ((64 + lq * 16) ^ swzr);
                const half8 fh   = *(const half8*)(w1f + fbase + 16);
                const half8 fl   = *(const half8*)(w1f + fbase + 48);
                const half8 zfh1 = *(const half8*)(zh + zo1);
                const half8 zfl1 = *(const half8*)(zl + zo1);
                a1A = __builtin_amdgcn_mfma_f32_16x16x32_f16(fh, zfh1, a1A, 0, 0, 0);
                a1A = __builtin_amdgcn_mfma_f32_16x16x32_f16(fl, zfh1, a1A, 0, 0, 0);
                a1A = __builtin_amdgcn_mfma_f32_16x16x32_f16(fh, zfl1, a1A, 0, 0, 0);
            }
            half4 ph, pl;
            #pragma unroll
            for (int r = 0; r < 4; ++r) {
                const float hv = fmaxf(a1A[r], 0.0f);
                const _Float16 hi = (_Float16)hv;
                ph[r] = hi; pl[r] = (_Float16)(hv - (float)hi);
            }
            const int hoff = l15 * 256 + ((w * 32 + lq * 8) ^ swzr);
            *(half4*)(hh + hoff) = ph;
            *(half4*)(hl + hoff) = pl;
        }
        bar_lgkm();

        // ---- GEMM2 (all 16 waves, 2 ntiles each); acc init from LDS ----
        f32x4 acc0 = *(const f32x4*)(b2s + b2slot);
        f32x4 acc1 = *(const f32x4*)(b2s + 16384 + b2slot);
        #pragma unroll
        for (int kt = 0; kt < 4; ++kt) {
            const int off = l15 * 256 + ((kt * 64 + lq * 16) ^ swzr);
            const half8 bh = *(const half8*)(hh + off);
            const half8 bl = *(const half8*)(hl + off);
            acc0 = __builtin_amdgcn_mfma_f32_16x16x32_f16(w2h[kt],     bh, acc0, 0, 0, 0);
            acc1 = __builtin_amdgcn_mfma_f32_16x16x32_f16(w2h[4 + kt], bh, acc1, 0, 0, 0);
            acc0 = __builtin_amdgcn_mfma_f32_16x16x32_f16(w2l[kt],     bh, acc0, 0, 0, 0);
            acc1 = __builtin_amdgcn_mfma_f32_16x16x32_f16(w2l[4 + kt], bh, acc1, 0, 0, 0);
            acc0 = __builtin_amdgcn_mfma_f32_16x16x32_f16(w2h[kt],     bl, acc0, 0, 0, 0);
            acc1 = __builtin_amdgcn_mfma_f32_16x16x32_f16(w2h[4 + kt], bl, acc1, 0, 0, 0);
        }

        // ---- tanh + i-contraction + register z update ----
        // lane (l15,lq), q: f-cols n=(2w+q)*16+lq*4+r; i=(lq&1)*4+r; kh=4w+2q+(lq>>1)
        const f32x4 dxv = cnext - ccur;
        float s0 = 0.f, s1 = 0.f;
        #pragma unroll
        for (int r = 0; r < 4; ++r) {
            s0 = fmaf(fast_tanh(acc0[r]), dxv[r], s0);
            s1 = fmaf(fast_tanh(acc1[r]), dxv[r], s1);
        }
        {
            const float tt0 = sum_xor16(s0);
            const float uu0 = sum_xor32(hi32 ? tt0 : 0.f);
            z4[0] += tt0; z4[1] += uu0;
            const float tt1 = sum_xor16(s1);
            const float uu1 = sum_xor32(hi32 ? tt1 : 0.f);
            z4[2] += tt1; z4[3] += uu1;
        }
        ccur = cnext;
        // ---- writeback + readout partial (owner lanes only) ----
        if (lq == 0) {
            half4 h4, l4;
            float rp = 0.f;
            #pragma unroll
            for (int j = 0; j < 4; ++j) {
                const _Float16 hi = (_Float16)z4[j];
                h4[j] = hi; l4[j] = (_Float16)(z4[j] - (float)hi);
                rp = fmaf(z4[j], wrs[j], rp);
            }
            const int zoff = l15 * 128 + ((w * 8) ^ swzr);
            *(half4*)(zh + zoff) = h4;
            *(half4*)(zl + zoff) = l4;
            part[w][l15] = rp;
        }
        bar_lgkm();
    }

    // ---- final readout: state 165 ----
    if (w == 15) {
        float v = part[lq * 4 + 0][l15] + part[lq * 4 + 1][l15]
                + part[lq * 4 + 2][l15] + part[lq * 4 + 3][l15];
        v = sum_xor32(sum_xor16(v));
        if (lq == 0) out[(size_t)(b0 + l15) * T_LEN + NSTEP] = v + brv;
    }
}

extern "C" void kernel_launch(void* const* d_in, const int* in_sizes, int n_in,
                              void* d_out, int out_size, void* d_ws, size_t ws_size,
                              hipStream_t stream) {
    const float* u0     = (const float*)d_in[0];
    const float* coeffs = (const float*)d_in[1];
    const float* W1     = (const float*)d_in[2];
    const float* b1     = (const float*)d_in[3];
    const float* W2     = (const float*)d_in[4];
    const float* b2     = (const float*)d_in[5];
    const float* Wi     = (const float*)d_in[6];
    const float* bi     = (const float*)d_in[7];
    const float* Wr     = (const float*)d_in[8];
    const float* br     = (const float*)d_in[9];
    cde_fused<<<NBLK, NT, 0, stream>>>(u0, coeffs, W1, b1, W2, b2, Wi, bi, Wr, br,
                                       (float*)d_out);
}

// Round 11
// 295.633 us; speedup vs baseline: 1.0270x; 1.0129x over previous
//
#include <hip/hip_runtime.h>

// Neural CDE forward, fused persistent kernel, split-f16 MFMA, transposed
// GEMMs. Round-11 = round-10 (16 waves, no spill) + schedule trims:
//  - bar_lgkm WITHOUT sched_barrier(0): lets the scheduler interleave
//    address setup / coeff handling across phase boundaries. Safe: all
//    ds_reads are C++ loads (compiler-tracked deps), cross-wave ordering
//    is still lgkmcnt(0)+s_barrier.
//  - all loop-invariant LDS byte offsets hoisted to pre-loop constants;
//    coeff and out pointers strength-reduced to moving pointers (no
//    per-step 64-bit address muls).
// Numerics unchanged: split-f16 (hi+lo), 3 MFMA terms per tile, f32 state.

#define NBLK 256
#define NT   1024
#define RB   16
#define T_LEN 166
#define NSTEP 165
#define IC   8
#define HID  64
#define MW   128
#define NF   512

typedef _Float16 half8 __attribute__((ext_vector_type(8)));
typedef _Float16 half4 __attribute__((ext_vector_type(4)));
typedef float    f32x4 __attribute__((ext_vector_type(4)));

__device__ __forceinline__ float fast_tanh(float x) {
    float e = __expf(2.0f * x);
    return 1.0f - 2.0f * __builtin_amdgcn_rcpf(e + 1.0f);
}

__device__ __forceinline__ void bar_lgkm() {
    asm volatile("s_waitcnt lgkmcnt(0)" ::: "memory");
    __builtin_amdgcn_s_barrier();
}

// x + x[lane^16] on all lanes (swap-direction independent).
__device__ __forceinline__ float sum_xor16(float x) {
#if __has_builtin(__builtin_amdgcn_permlane16_swap)
    auto r = __builtin_amdgcn_permlane16_swap(__float_as_uint(x), __float_as_uint(x), false, false);
    return __uint_as_float(r[0]) + __uint_as_float(r[1]);
#else
    return x + __shfl_xor(x, 16, 64);
#endif
}
// x + x[lane^32] on all lanes.
__device__ __forceinline__ float sum_xor32(float x) {
#if __has_builtin(__builtin_amdgcn_permlane32_swap)
    auto r = __builtin_amdgcn_permlane32_swap(__float_as_uint(x), __float_as_uint(x), false, false);
    return __uint_as_float(r[0]) + __uint_as_float(r[1]);
#else
    return x + __shfl_xor(x, 32, 64);
#endif
}

__global__ __launch_bounds__(NT, 4)
void cde_fused(const float* __restrict__ u0, const float* __restrict__ coeffs,
               const float* __restrict__ W1, const float* __restrict__ b1,
               const float* __restrict__ W2, const float* __restrict__ b2,
               const float* __restrict__ Wi, const float* __restrict__ bi,
               const float* __restrict__ Wr, const float* __restrict__ br,
               float* __restrict__ out)
{
    __shared__ __align__(16) unsigned char hh[RB * 256];    // h hi: 16 x 128 f16 (swizzled)
    __shared__ __align__(16) unsigned char hl[RB * 256];    // h lo
    __shared__ __align__(16) unsigned char zh[RB * 128];    // z hi: 16 x 64 f16 (swizzled)
    __shared__ __align__(16) unsigned char zl[RB * 128];    // z lo
    __shared__ __align__(16) unsigned char w1f[8 * 64 * 80];// W1 frags + b1 per (wave,lane)
    __shared__ __align__(16) unsigned char b2s[2 * 16 * 64 * 16]; // b2 acc-init planes
    __shared__ float part[16][17];                          // readout partials [wave][batch]

    const int tid  = threadIdx.x;
    const int lane = tid & 63;
    const int w    = tid >> 6;      // wave 0..15
    const int l15  = lane & 15;     // batch row in MFMA D
    const int lq   = lane >> 4;     // 0..3
    const bool hi32 = (lane & 32) != 0;
    const int swzr = (l15 & 7) << 4;
    const int b0   = blockIdx.x * RB;

    // ---- stage split W2 (2 ntiles per wave) into registers/AGPRs ----
    half8 w2h[8], w2l[8];
    #pragma unroll
    for (int q = 0; q < 2; ++q) {
        #pragma unroll
        for (int kt = 0; kt < 4; ++kt) {
            const int krow = kt * 32 + lq * 8;
            const int ncol = (w * 2 + q) * 16 + l15;
            half8 vh, vl;
            #pragma unroll
            for (int j = 0; j < 8; ++j) {
                const float x = W2[(krow + j) * NF + ncol];
                const _Float16 hi = (_Float16)x;
                vh[j] = hi; vl[j] = (_Float16)(x - (float)hi);
            }
            w2h[q * 4 + kt] = vh; w2l[q * 4 + kt] = vl;
        }
    }
    // ---- stage b2 acc-init into LDS planes (16B per lane, conflict-free) ----
    const int b2slot = (w * 64 + lane) * 16;
    *(f32x4*)(b2s + b2slot)         = *(const f32x4*)(b2 + (w * 2 + 0) * 16 + lq * 4);
    *(f32x4*)(b2s + 16384 + b2slot) = *(const f32x4*)(b2 + (w * 2 + 1) * 16 + lq * 4);

    // ---- stage split W1 fragments + b1 into LDS (waves 0-7) ----
    const int fbase = (w * 64 + lane) * 80;   // 80B slot: 4x16B frags + 16B b1
    if (w < 8) {
        #pragma unroll
        for (int kt = 0; kt < 2; ++kt) {
            const int krow = kt * 32 + lq * 8;
            const int ncol = w * 16 + l15;
            half8 vh, vl;
            #pragma unroll
            for (int j = 0; j < 8; ++j) {
                const float x = W1[(krow + j) * MW + ncol];
                const _Float16 hi = (_Float16)x;
                vh[j] = hi; vl[j] = (_Float16)(x - (float)hi);
            }
            *(half8*)(w1f + fbase + kt * 16)      = vh;   // h0 @0, h1 @16
            *(half8*)(w1f + fbase + 32 + kt * 16) = vl;   // l0 @32, l1 @48
        }
        *(f32x4*)(w1f + fbase + 64) = *(const f32x4*)(b1 + w * 16 + lq * 4);
    }

    // readout weights for this wave's 4 channels (wave-uniform -> scalar)
    const int w_u = __builtin_amdgcn_readfirstlane(w);
    float wrs[4];
    #pragma unroll
    for (int j = 0; j < 4; ++j) wrs[j] = Wr[w_u * 4 + j];
    const float brv = br[0];

    // ---- hoisted loop-invariant LDS byte offsets ----
    const int zo0  = l15 * 128 + ((lq * 16) ^ swzr);          // GEMM1 z frag kt0
    const int zo1  = l15 * 128 + ((64 + lq * 16) ^ swzr);     // GEMM1 z frag kt1
    const int hoff = l15 * 256 + ((w * 32 + lq * 8) ^ swzr);  // GEMM1 h store
    const int off0 = l15 * 256 + ((0 * 64 + lq * 16) ^ swzr); // GEMM2 h frag kt0
    const int off1 = l15 * 256 + ((1 * 64 + lq * 16) ^ swzr);
    const int off2 = l15 * 256 + ((2 * 64 + lq * 16) ^ swzr);
    const int off3 = l15 * 256 + ((3 * 64 + lq * 16) ^ swzr);
    const int zoW  = l15 * 128 + ((w * 8) ^ swzr);            // z writeback

    // ---- z0: owner lane (lq==0) holds channels [4w, 4w+4) of batch l15 ----
    float z4[4];
    {
        float uu7[7];
        const float* ur = u0 + (size_t)(b0 + l15) * 7;
        #pragma unroll
        for (int c = 0; c < 7; ++c) uu7[c] = ur[c];
        #pragma unroll
        for (int j = 0; j < 4; ++j) {
            float a = bi[w * 4 + j];
            #pragma unroll
            for (int c = 0; c < 7; ++c) a = fmaf(uu7[c], Wi[c * HID + w * 4 + j], a);
            z4[j] = a;
        }
    }
    if (lq == 0) {
        half4 h4, l4;
        float rp = 0.f;
        #pragma unroll
        for (int j = 0; j < 4; ++j) {
            const _Float16 hi = (_Float16)z4[j];
            h4[j] = hi; l4[j] = (_Float16)(z4[j] - (float)hi);
            rp = fmaf(z4[j], wrs[j], rp);
        }
        *(half4*)(zh + zoW) = h4;
        *(half4*)(zl + zoW) = l4;
        part[w][l15] = rp;
    }
    // per-lane coeff stream (moving pointer, no per-step address mul)
    const float* cptr = coeffs + (size_t)(b0 + l15) * T_LEN * IC + (lq & 1) * 4;
    f32x4 ccur = *(const f32x4*)(cptr);
    float* outp = out + (size_t)(b0 + l15) * T_LEN;   // wave-15 moving base
    __syncthreads();

    for (int t = 0; t < NSTEP; ++t) {
        // prefetch next coeff chunk at loop TOP (hides under GEMM1+barrier)
        const f32x4 cnext = *(const f32x4*)(cptr + IC);
        cptr += IC;

        // ---- readout finalize for state t (wave 15, idle in GEMM1 phase) ----
        if (w == 15) {
            float v = part[lq * 4 + 0][l15] + part[lq * 4 + 1][l15]
                    + part[lq * 4 + 2][l15] + part[lq * 4 + 3][l15];
            v = sum_xor32(sum_xor16(v));
            if (lq == 0) outp[t] = v + brv;
        }

        // ---- GEMM1 (waves 0-7): h^T = W1^T @ z^T, relu, split store ----
        if (w < 8) {
            f32x4 a1A = *(const f32x4*)(w1f + fbase + 64);     // b1 from LDS slot
            {
                const half8 fh   = *(const half8*)(w1f + fbase);
                const half8 fl   = *(const half8*)(w1f + fbase + 32);
                const half8 zfh0 = *(const half8*)(zh + zo0);
                const half8 zfl0 = *(const half8*)(zl + zo0);
                a1A = __builtin_amdgcn_mfma_f32_16x16x32_f16(fh, zfh0, a1A, 0, 0, 0);
                a1A = __builtin_amdgcn_mfma_f32_16x16x32_f16(fl, zfh0, a1A, 0, 0, 0);
                a1A = __builtin_amdgcn_mfma_f32_16x16x32_f16(fh, zfl0, a1A, 0, 0, 0);
            }
            {
                const half8 fh   = *(const half8*)(w1f + fbase + 16);
                const half8 fl   = *(const half8*)(w1f + fbase + 48);
                const half8 zfh1 = *(const half8*)(zh + zo1);
                const half8 zfl1 = *(const half8*)(zl + zo1);
                a1A = __builtin_amdgcn_mfma_f32_16x16x32_f16(fh, zfh1, a1A, 0, 0, 0);
                a1A = __builtin_amdgcn_mfma_f32_16x16x32_f16(fl, zfh1, a1A, 0, 0, 0);
                a1A = __builtin_amdgcn_mfma_f32_16x16x32_f16(fh, zfl1, a1A, 0, 0, 0);
            }
            half4 ph, pl;
            #pragma unroll
            for (int r = 0; r < 4; ++r) {
                const float hv = fmaxf(a1A[r], 0.0f);
                const _Float16 hi = (_Float16)hv;
                ph[r] = hi; pl[r] = (_Float16)(hv - (float)hi);
            }
            *(half4*)(hh + hoff) = ph;
            *(half4*)(hl + hoff) = pl;
        }
        bar_lgkm();

        // ---- GEMM2 (all 16 waves, 2 ntiles each); acc init from LDS ----
        f32x4 acc0 = *(const f32x4*)(b2s + b2slot);
        f32x4 acc1 = *(const f32x4*)(b2s + 16384 + b2slot);
        {
            const half8 bh = *(const half8*)(hh + off0);
            const half8 bl = *(const half8*)(hl + off0);
            acc0 = __builtin_amdgcn_mfma_f32_16x16x32_f16(w2h[0], bh, acc0, 0, 0, 0);
            acc1 = __builtin_amdgcn_mfma_f32_16x16x32_f16(w2h[4], bh, acc1, 0, 0, 0);
            acc0 = __builtin_amdgcn_mfma_f32_16x16x32_f16(w2l[0], bh, acc0, 0, 0, 0);
            acc1 = __builtin_amdgcn_mfma_f32_16x16x32_f16(w2l[4], bh, acc1, 0, 0, 0);
            acc0 = __builtin_amdgcn_mfma_f32_16x16x32_f16(w2h[0], bl, acc0, 0, 0, 0);
            acc1 = __builtin_amdgcn_mfma_f32_16x16x32_f16(w2h[4], bl, acc1, 0, 0, 0);
        }
        {
            const half8 bh = *(const half8*)(hh + off1);
            const half8 bl = *(const half8*)(hl + off1);
            acc0 = __builtin_amdgcn_mfma_f32_16x16x32_f16(w2h[1], bh, acc0, 0, 0, 0);
            acc1 = __builtin_amdgcn_mfma_f32_16x16x32_f16(w2h[5], bh, acc1, 0, 0, 0);
            acc0 = __builtin_amdgcn_mfma_f32_16x16x32_f16(w2l[1], bh, acc0, 0, 0, 0);
            acc1 = __builtin_amdgcn_mfma_f32_16x16x32_f16(w2l[5], bh, acc1, 0, 0, 0);
            acc0 = __builtin_amdgcn_mfma_f32_16x16x32_f16(w2h[1], bl, acc0, 0, 0, 0);
            acc1 = __builtin_amdgcn_mfma_f32_16x16x32_f16(w2h[5], bl, acc1, 0, 0, 0);
        }
        {
            const half8 bh = *(const half8*)(hh + off2);
            const half8 bl = *(const half8*)(hl + off2);
            acc0 = __builtin_amdgcn_mfma_f32_16x16x32_f16(w2h[2], bh, acc0, 0, 0, 0);
            acc1 = __builtin_amdgcn_mfma_f32_16x16x32_f16(w2h[6], bh, acc1, 0, 0, 0);
            acc0 = __builtin_amdgcn_mfma_f32_16x16x32_f16(w2l[2], bh, acc0, 0, 0, 0);
            acc1 = __builtin_amdgcn_mfma_f32_16x16x32_f16(w2l[6], bh, acc1, 0, 0, 0);
            acc0 = __builtin_amdgcn_mfma_f32_16x16x32_f16(w2h[2], bl, acc0, 0, 0, 0);
            acc1 = __builtin_amdgcn_mfma_f32_16x16x32_f16(w2h[6], bl, acc1, 0, 0, 0);
        }
        {
            const half8 bh = *(const half8*)(hh + off3);
            const half8 bl = *(const half8*)(hl + off3);
            acc0 = __builtin_amdgcn_mfma_f32_16x16x32_f16(w2h[3], bh, acc0, 0, 0, 0);
            acc1 = __builtin_amdgcn_mfma_f32_16x16x32_f16(w2h[7], bh, acc1, 0, 0, 0);
            acc0 = __builtin_amdgcn_mfma_f32_16x16x32_f16(w2l[3], bh, acc0, 0, 0, 0);
            acc1 = __builtin_amdgcn_mfma_f32_16x16x32_f16(w2l[7], bh, acc1, 0, 0, 0);
            acc0 = __builtin_amdgcn_mfma_f32_16x16x32_f16(w2h[3], bl, acc0, 0, 0, 0);
            acc1 = __builtin_amdgcn_mfma_f32_16x16x32_f16(w2h[7], bl, acc1, 0, 0, 0);
        }

        // ---- tanh + i-contraction + register z update ----
        // lane (l15,lq), q: f-cols n=(2w+q)*16+lq*4+r; i=(lq&1)*4+r; kh=4w+2q+(lq>>1)
        const f32x4 dxv = cnext - ccur;
        float s0 = 0.f, s1 = 0.f;
        #pragma unroll
        for (int r = 0; r < 4; ++r) {
            s0 = fmaf(fast_tanh(acc0[r]), dxv[r], s0);
            s1 = fmaf(fast_tanh(acc1[r]), dxv[r], s1);
        }
        {
            const float tt0 = sum_xor16(s0);
            const float uu0 = sum_xor32(hi32 ? tt0 : 0.f);
            z4[0] += tt0; z4[1] += uu0;
            const float tt1 = sum_xor16(s1);
            const float uu1 = sum_xor32(hi32 ? tt1 : 0.f);
            z4[2] += tt1; z4[3] += uu1;
        }
        ccur = cnext;
        // ---- writeback + readout partial (owner lanes only) ----
        if (lq == 0) {
            half4 h4, l4;
            float rp = 0.f;
            #pragma unroll
            for (int j = 0; j < 4; ++j) {
                const _Float16 hi = (_Float16)z4[j];
                h4[j] = hi; l4[j] = (_Float16)(z4[j] - (float)hi);
                rp = fmaf(z4[j], wrs[j], rp);
            }
            *(half4*)(zh + zoW) = h4;
            *(half4*)(zl + zoW) = l4;
            part[w][l15] = rp;
        }
        bar_lgkm();
    }

    // ---- final readout: state 165 ----
    if (w == 15) {
        float v = part[lq * 4 + 0][l15] + part[lq * 4 + 1][l15]
                + part[lq * 4 + 2][l15] + part[lq * 4 + 3][l15];
        v = sum_xor32(sum_xor16(v));
        if (lq == 0) outp[NSTEP] = v + brv;
    }
}

extern "C" void kernel_launch(void* const* d_in, const int* in_sizes, int n_in,
                              void* d_out, int out_size, void* d_ws, size_t ws_size,
                              hipStream_t stream) {
    const float* u0     = (const float*)d_in[0];
    const float* coeffs = (const float*)d_in[1];
    const float* W1     = (const float*)d_in[2];
    const float* b1     = (const float*)d_in[3];
    const float* W2     = (const float*)d_in[4];
    const float* b2     = (const float*)d_in[5];
    const float* Wi     = (const float*)d_in[6];
    const float* bi     = (const float*)d_in[7];
    const float* Wr     = (const float*)d_in[8];
    const float* br     = (const float*)d_in[9];
    cde_fused<<<NBLK, NT, 0, stream>>>(u0, coeffs, W1, b1, W2, b2, Wi, bi, Wr, br,
                                       (float*)d_out);
}